// Round 3
// baseline (264.258 us; speedup 1.0000x reference)
//
#include <hip/hip_runtime.h>

// Problem constants (fixed by the reference setup)
#define BB 8
#define SS 4096
#define DD 1024
#define HH 16
#define HD 64
#define NR 32
#define NROWS (BB * SS * HH)      // 524288 head-vectors of length 64
#define NGRP (NROWS / 16)         // 32768 groups of 16 rows (one s-position each)
#define GPW 4                     // groups per wave
#define GPB (4 * GPW)             // groups per block (4 waves)
#define NBLK (NGRP / GPB)         // 2048 blocks

typedef __attribute__((ext_vector_type(8))) short bf16x8;   // 8 bf16 (4 VGPRs)
typedef __attribute__((ext_vector_type(4))) float f32x4;

// ---------------------------------------------------------------------------
// Kernel A: build C = R0*R1*...*R31 * r_matrix via row ops, then pack
// A = C^T into per-lane MFMA fragment order, split into bf16 hi/lo.
// Apack layout (ushort): [hi/lo][tile t(4)][kstep ks(2)][lane(64)][j(8)]
//   A[i][k] = C[k][i];  i = t*16 + (lane&15);  k = ks*32 + (lane>>4)*8 + j
// ---------------------------------------------------------------------------
__global__ __launch_bounds__(256) void build_pack_kernel(
    const float* __restrict__ thetas,
    const float* __restrict__ r_pairs,
    const float* __restrict__ theta_scale,
    const float* __restrict__ r_matrix,
    unsigned short* __restrict__ Apack)
{
    __shared__ float W[64 * 68];     // 64x64, row stride 68 (bank spread)
    __shared__ int   ii[NR], jj[NR];
    __shared__ float cc[NR], ssn[NR];

    const int t = threadIdx.x;

#pragma unroll
    for (int it = 0; it < 16; ++it) {
        int idx = t + 256 * it;                  // 0..4095
        W[(idx >> 6) * 68 + (idx & 63)] = r_matrix[idx];
    }
    if (t < NR) {
        ii[t] = (int)r_pairs[2 * t];             // truncation == astype(int32) for >=0
        jj[t] = (int)r_pairs[2 * t + 1];
        float th = thetas[t] * theta_scale[0];
        cc[t]  = cosf(th);
        ssn[t] = sinf(th);
    }
    __syncthreads();

    if (t < 64) {
        for (int k = NR - 1; k >= 0; --k) {
            int i = ii[k], j = jj[k];
            float c = cc[k], s = ssn[k];
            float xi = W[i * 68 + t];
            float xj = W[j * 68 + t];
            if (i == j) {
                W[i * 68 + t] = c * xi;
            } else {
                W[i * 68 + t] = c * xi - s * xj;
                W[j * 68 + t] = s * xi + c * xj;
            }
        }
    }
    __syncthreads();

    // Pack C^T fragments, split-bf16 (truncation split: hi = top16, lo = top16(v-hi))
#pragma unroll
    for (int it = 0; it < 16; ++it) {
        int flat = t + 256 * it;                 // 0..4095 = ((tt*2+ks)*64+lane)*8+j
        int j    = flat & 7;
        int lane = (flat >> 3) & 63;
        int ks   = (flat >> 9) & 1;
        int tt   = flat >> 10;
        int i    = tt * 16 + (lane & 15);
        int k    = ks * 32 + ((lane >> 4) << 3) + j;
        float v  = W[k * 68 + i];
        unsigned u  = __float_as_uint(v);
        unsigned uh = u & 0xFFFF0000u;
        float fl    = v - __uint_as_float(uh);
        Apack[flat]        = (unsigned short)(uh >> 16);
        Apack[4096 + flat] = (unsigned short)(__float_as_uint(fl) >> 16);
    }
}

// ---------------------------------------------------------------------------
// Split 8 f32 into bf16 hi/lo fragments (truncation split).
// ---------------------------------------------------------------------------
__device__ __forceinline__ void split8(const float4 a, const float4 b,
                                       bf16x8& hi, bf16x8& lo)
{
    const float f[8] = {a.x, a.y, a.z, a.w, b.x, b.y, b.z, b.w};
#pragma unroll
    for (int j = 0; j < 8; ++j) {
        unsigned u  = __float_as_uint(f[j]);
        unsigned uh = u & 0xFFFF0000u;
        hi[j] = (short)(uh >> 16);
        float fl = f[j] - __uint_as_float(uh);
        lo[j] = (short)(__float_as_uint(fl) >> 16);
    }
}

// ---------------------------------------------------------------------------
// Main kernel: per 16-row group (one s-position), y^T = C^T · x^T via
// mfma_f32_16x16x32_bf16 (3-term split-bf16). Epilogue: one shfl_xor(16)
// exchange per tile pair gives each lane 8 CONSECUTIVE y-cols, so RoPE
// stores are 4 coalesced nontemporal float4 per group (16 rows x 64B
// contiguous segments per instruction) instead of 8 scattered float2.
// ---------------------------------------------------------------------------
__global__ __launch_bounds__(256, 4) void rope_mfma_kernel(
    const float* __restrict__ x,
    const unsigned short* __restrict__ Apack,
    const float* __restrict__ inv_freq,
    float* __restrict__ out)
{
    const int lane = threadIdx.x & 63;
    const int wv   = threadIdx.x >> 6;
    const int q    = lane >> 4;          // k-quarter / y-col quarter
    const int rr   = lane & 15;          // x-row within group
    const int qlo  = q & 1;
    const int qhi  = q >> 1;
    const bool odd = qlo != 0;

    // Loop-invariant C^T fragments (hi/lo), 64 VGPRs total
    bf16x8 Ah[4][2], Al[4][2];
    {
        const bf16x8* Ap = (const bf16x8*)Apack;
#pragma unroll
        for (int tt = 0; tt < 4; ++tt)
#pragma unroll
            for (int ks = 0; ks < 2; ++ks) {
                Ah[tt][ks] = Ap[(tt * 2 + ks) * 64 + lane];
                Al[tt][ks] = Ap[512 + (tt * 2 + ks) * 64 + lane];
            }
    }
    // Loop-invariant inv_freq for this lane's two output col-blocks.
    // Block pr covers out cols [4*c', 4*c'+4) with c' = 2*qlo + qhi + 4*pr.
    float4 invf4[2];
#pragma unroll
    for (int pr = 0; pr < 2; ++pr)
        invf4[pr] = *(const float4*)&inv_freq[8 * qlo + 4 * qhi + 16 * pr];

    int g = blockIdx.x * GPB + wv * GPW;

    // Prologue load (group g): 8 floats per k-step, 2 k-steps
    const float* xr = x + ((size_t)g * 16 + rr) * 64 + q * 8;
    float4 fa0 = *(const float4*)(xr);
    float4 fa1 = *(const float4*)(xr + 4);
    float4 fa2 = *(const float4*)(xr + 32);
    float4 fa3 = *(const float4*)(xr + 36);

#pragma unroll 1
    for (int gi = 0; gi < GPW; ++gi, ++g) {
        // 1-deep prefetch of next group's x (uniform branch)
        float4 fb0 = fa0, fb1 = fa1, fb2 = fa2, fb3 = fa3;
        if (gi + 1 < GPW) {
            const float* xn = x + ((size_t)(g + 1) * 16 + rr) * 64 + q * 8;
            fb0 = *(const float4*)(xn);
            fb1 = *(const float4*)(xn + 4);
            fb2 = *(const float4*)(xn + 32);
            fb3 = *(const float4*)(xn + 36);
        }

        bf16x8 Bh0, Bl0, Bh1, Bl1;
        split8(fa0, fa1, Bh0, Bl0);
        split8(fa2, fa3, Bh1, Bl1);

        f32x4 acc[4];
#pragma unroll
        for (int tt = 0; tt < 4; ++tt) {
            f32x4 a = {0.f, 0.f, 0.f, 0.f};
            a = __builtin_amdgcn_mfma_f32_16x16x32_bf16(Ah[tt][0], Bh0, a, 0, 0, 0);
            a = __builtin_amdgcn_mfma_f32_16x16x32_bf16(Ah[tt][1], Bh1, a, 0, 0, 0);
            a = __builtin_amdgcn_mfma_f32_16x16x32_bf16(Al[tt][0], Bh0, a, 0, 0, 0);
            a = __builtin_amdgcn_mfma_f32_16x16x32_bf16(Al[tt][1], Bh1, a, 0, 0, 0);
            a = __builtin_amdgcn_mfma_f32_16x16x32_bf16(Ah[tt][0], Bl0, a, 0, 0, 0);
            a = __builtin_amdgcn_mfma_f32_16x16x32_bf16(Ah[tt][1], Bl1, a, 0, 0, 0);
            acc[tt] = a;
        }

        // Epilogue. Lane (q,rr) holds y[rr][t*16 + q*4 + r] (t=0..3, r=0..3).
        // Exchange with lane^16 (q^1): per tile pair (2pr, 2pr+1), even-q lane
        // keeps tile 2pr and gains partner's 4 cols; odd-q keeps 2pr+1.
        // Result: lane owns y[rr][8c' .. 8c'+8) for c' = 2*qlo + qhi + 4*pr.
        const float pos = (float)(g & (SS - 1));
        float* orow = out + ((size_t)g * 16 + rr) * 64;

#pragma unroll
        for (int pr = 0; pr < 2; ++pr) {
            const f32x4 aE = acc[2 * pr];
            const f32x4 aO = acc[2 * pr + 1];
            float y8[8];
#pragma unroll
            for (int r = 0; r < 4; ++r) {
                float send = odd ? aE[r] : aO[r];
                float recv = __shfl_xor(send, 16, 64);
                y8[r]     = odd ? recv  : aE[r];
                y8[4 + r] = odd ? aO[r] : recv;
            }
            const float4 fr = invf4[pr];
            float sn[4], cs[4];
            __sincosf(pos * fr.x, &sn[0], &cs[0]);
            __sincosf(pos * fr.y, &sn[1], &cs[1]);
            __sincosf(pos * fr.z, &sn[2], &cs[2]);
            __sincosf(pos * fr.w, &sn[3], &cs[3]);
            f32x4 o1, o2;
            o1[0] = y8[0] * cs[0] - y8[1] * sn[0];
            o1[1] = y8[2] * cs[1] - y8[3] * sn[1];
            o1[2] = y8[4] * cs[2] - y8[5] * sn[2];
            o1[3] = y8[6] * cs[3] - y8[7] * sn[3];
            o2[0] = y8[0] * sn[0] + y8[1] * cs[0];
            o2[1] = y8[2] * sn[1] + y8[3] * cs[1];
            o2[2] = y8[4] * sn[2] + y8[5] * cs[2];
            o2[3] = y8[6] * sn[3] + y8[7] * cs[3];
            const int cb4 = 8 * qlo + 4 * qhi + 16 * pr;   // 4*c'
            __builtin_nontemporal_store(o1, (f32x4*)(orow + cb4));
            __builtin_nontemporal_store(o2, (f32x4*)(orow + 32 + cb4));
        }

        fa0 = fb0; fa1 = fb1; fa2 = fb2; fa3 = fb3;
    }
}

// ---------------------------------------------------------------------------
extern "C" void kernel_launch(void* const* d_in, const int* in_sizes, int n_in,
                              void* d_out, int out_size, void* d_ws, size_t ws_size,
                              hipStream_t stream)
{
    const float* x           = (const float*)d_in[0];
    const float* thetas      = (const float*)d_in[1];
    const float* r_pairs     = (const float*)d_in[2];
    const float* theta_scale = (const float*)d_in[3];
    // d_in[4] = n_rots_scale (unused by the reference)
    const float* r_matrix    = (const float*)d_in[5];
    const float* inv_freq    = (const float*)d_in[6];
    float* out = (float*)d_out;
    unsigned short* Apack = (unsigned short*)d_ws;   // 8192 ushort = 16 KB

    build_pack_kernel<<<1, 256, 0, stream>>>(thetas, r_pairs, theta_scale,
                                             r_matrix, Apack);
    rope_mfma_kernel<<<NBLK, 256, 0, stream>>>(x, Apack, inv_freq, out);
}

// Round 4
// 246.241 us; speedup vs baseline: 1.0732x; 1.0732x over previous
//
#include <hip/hip_runtime.h>

// Problem constants (fixed by the reference setup)
#define BB 8
#define SS 4096
#define DD 1024
#define HH 16
#define HD 64
#define NR 32
#define NROWS (BB * SS * HH)      // 524288 head-vectors of length 64
#define NGRP (NROWS / 16)         // 32768 groups of 16 rows (one s-position each)
#define GPW 2                     // groups per wave (both loaded upfront)
#define GPB (4 * GPW)             // groups per block (4 waves)
#define NBLK (NGRP / GPB)         // 4096 blocks

typedef __attribute__((ext_vector_type(8))) short bf16x8;   // 8 bf16 (4 VGPRs)
typedef __attribute__((ext_vector_type(4))) float f32x4;

// ---------------------------------------------------------------------------
// Kernel A: build C = R0*R1*...*R31 * r_matrix via row ops, then pack
// A = C^T into per-lane MFMA fragment order, split into bf16 hi/lo.
// Apack layout (ushort): [hi/lo][tile t(4)][kstep ks(2)][lane(64)][j(8)]
//   A[i][k] = C[k][i];  i = t*16 + (lane&15);  k = ks*32 + (lane>>4)*8 + j
// ---------------------------------------------------------------------------
__global__ __launch_bounds__(256) void build_pack_kernel(
    const float* __restrict__ thetas,
    const float* __restrict__ r_pairs,
    const float* __restrict__ theta_scale,
    const float* __restrict__ r_matrix,
    unsigned short* __restrict__ Apack)
{
    __shared__ float W[64 * 68];     // 64x64, row stride 68 (bank spread)
    __shared__ int   ii[NR], jj[NR];
    __shared__ float cc[NR], ssn[NR];

    const int t = threadIdx.x;

#pragma unroll
    for (int it = 0; it < 16; ++it) {
        int idx = t + 256 * it;                  // 0..4095
        W[(idx >> 6) * 68 + (idx & 63)] = r_matrix[idx];
    }
    if (t < NR) {
        ii[t] = (int)r_pairs[2 * t];             // truncation == astype(int32) for >=0
        jj[t] = (int)r_pairs[2 * t + 1];
        float th = thetas[t] * theta_scale[0];
        cc[t]  = cosf(th);
        ssn[t] = sinf(th);
    }
    __syncthreads();

    if (t < 64) {
        for (int k = NR - 1; k >= 0; --k) {
            int i = ii[k], j = jj[k];
            float c = cc[k], s = ssn[k];
            float xi = W[i * 68 + t];
            float xj = W[j * 68 + t];
            if (i == j) {
                W[i * 68 + t] = c * xi;
            } else {
                W[i * 68 + t] = c * xi - s * xj;
                W[j * 68 + t] = s * xi + c * xj;
            }
        }
    }
    __syncthreads();

    // Pack C^T fragments, split-bf16 (truncation split: hi = top16, lo = top16(v-hi))
#pragma unroll
    for (int it = 0; it < 16; ++it) {
        int flat = t + 256 * it;                 // 0..4095 = ((tt*2+ks)*64+lane)*8+j
        int j    = flat & 7;
        int lane = (flat >> 3) & 63;
        int ks   = (flat >> 9) & 1;
        int tt   = flat >> 10;
        int i    = tt * 16 + (lane & 15);
        int k    = ks * 32 + ((lane >> 4) << 3) + j;
        float v  = W[k * 68 + i];
        unsigned u  = __float_as_uint(v);
        unsigned uh = u & 0xFFFF0000u;
        float fl    = v - __uint_as_float(uh);
        Apack[flat]        = (unsigned short)(uh >> 16);
        Apack[4096 + flat] = (unsigned short)(__float_as_uint(fl) >> 16);
    }
}

// ---------------------------------------------------------------------------
// Split 8 f32 into bf16 hi/lo fragments (truncation split).
// ---------------------------------------------------------------------------
__device__ __forceinline__ void split8(const float4 a, const float4 b,
                                       bf16x8& hi, bf16x8& lo)
{
    const float f[8] = {a.x, a.y, a.z, a.w, b.x, b.y, b.z, b.w};
#pragma unroll
    for (int j = 0; j < 8; ++j) {
        unsigned u  = __float_as_uint(f[j]);
        unsigned uh = u & 0xFFFF0000u;
        hi[j] = (short)(uh >> 16);
        float fl = f[j] - __uint_as_float(uh);
        lo[j] = (short)(__float_as_uint(fl) >> 16);
    }
}

// ---------------------------------------------------------------------------
// RoPE epilogue for one group's accumulator tile set (verified permutation:
// shfl_xor(16) pairs tiles so each lane owns 8 consecutive y-cols; two
// coalesced float4 stores per pr). Inlined, all indices static after unroll.
// ---------------------------------------------------------------------------
__device__ __forceinline__ void epilogue(
    int g, const f32x4 acc[4], int rr, bool odd, int qlo, int qhi,
    const float4 invf4[2], float* __restrict__ out)
{
    const float pos = (float)(g & (SS - 1));
    float* orow = out + ((size_t)g * 16 + rr) * 64;
#pragma unroll
    for (int pr = 0; pr < 2; ++pr) {
        const f32x4 aE = acc[2 * pr];
        const f32x4 aO = acc[2 * pr + 1];
        float y8[8];
#pragma unroll
        for (int r = 0; r < 4; ++r) {
            float send = odd ? aE[r] : aO[r];
            float recv = __shfl_xor(send, 16, 64);
            y8[r]     = odd ? recv  : aE[r];
            y8[4 + r] = odd ? aO[r] : recv;
        }
        const float4 fr = invf4[pr];
        float sn[4], cs[4];
        __sincosf(pos * fr.x, &sn[0], &cs[0]);
        __sincosf(pos * fr.y, &sn[1], &cs[1]);
        __sincosf(pos * fr.z, &sn[2], &cs[2]);
        __sincosf(pos * fr.w, &sn[3], &cs[3]);
        f32x4 o1, o2;
        o1[0] = y8[0] * cs[0] - y8[1] * sn[0];
        o1[1] = y8[2] * cs[1] - y8[3] * sn[1];
        o1[2] = y8[4] * cs[2] - y8[5] * sn[2];
        o1[3] = y8[6] * cs[3] - y8[7] * sn[3];
        o2[0] = y8[0] * sn[0] + y8[1] * cs[0];
        o2[1] = y8[2] * sn[1] + y8[3] * cs[1];
        o2[2] = y8[4] * sn[2] + y8[5] * cs[2];
        o2[3] = y8[6] * sn[3] + y8[7] * cs[3];
        const int cb4 = 8 * qlo + 4 * qhi + 16 * pr;   // 4*c'
        *(f32x4*)(orow + cb4)      = o1;
        *(f32x4*)(orow + 32 + cb4) = o2;
    }
}

// ---------------------------------------------------------------------------
// Main kernel. Changes vs r3 for concurrency:
//  - A fragments live in LDS (16 KB staged once/block) -> ~64 fewer VGPRs
//  - all 8 x-loads (2 groups) issued upfront, tt-outer interleaves the two
//    groups' MFMA chains
//  - 4096 blocks, plain (non-nt) stores
// ---------------------------------------------------------------------------
__global__ __launch_bounds__(256, 4) void rope_mfma_kernel(
    const float* __restrict__ x,
    const unsigned short* __restrict__ Apack,
    const float* __restrict__ inv_freq,
    float* __restrict__ out)
{
    __shared__ unsigned short Asm[8192];     // 16 KB: packed A (hi 8 KB, lo 8 KB)

    const int t = threadIdx.x;

    // Stage Apack -> LDS (L2-hot after first blocks): 4 float4 per thread
    {
        const f32x4* src = (const f32x4*)Apack;
        f32x4*       dst = (f32x4*)Asm;
#pragma unroll
        for (int it = 0; it < 4; ++it)
            dst[t + 256 * it] = src[t + 256 * it];
    }
    __syncthreads();

    const int lane = t & 63;
    const int wv   = t >> 6;
    const int q    = lane >> 4;          // k-quarter / y-col quarter
    const int rr   = lane & 15;          // x-row within group
    const int qlo  = q & 1;
    const int qhi  = q >> 1;
    const bool odd = qlo != 0;

    float4 invf4[2];
#pragma unroll
    for (int pr = 0; pr < 2; ++pr)
        invf4[pr] = *(const float4*)&inv_freq[8 * qlo + 4 * qhi + 16 * pr];

    const int g0 = blockIdx.x * GPB + wv * GPW;

    // Upfront x loads for BOTH groups: 8 dwordx4 in flight per lane
    const float* xr0 = x + ((size_t)g0 * 16 + rr) * 64 + q * 8;
    const float4 f00 = *(const float4*)(xr0);
    const float4 f01 = *(const float4*)(xr0 + 4);
    const float4 f02 = *(const float4*)(xr0 + 32);
    const float4 f03 = *(const float4*)(xr0 + 36);
    const float* xr1 = xr0 + 1024;                    // next group = +16*64 floats
    const float4 f10 = *(const float4*)(xr1);
    const float4 f11 = *(const float4*)(xr1 + 4);
    const float4 f12 = *(const float4*)(xr1 + 32);
    const float4 f13 = *(const float4*)(xr1 + 36);

    bf16x8 B0h0, B0l0, B0h1, B0l1;
    bf16x8 B1h0, B1l0, B1h1, B1l1;
    split8(f00, f01, B0h0, B0l0);
    split8(f02, f03, B0h1, B0l1);
    split8(f10, f11, B1h0, B1l0);
    split8(f12, f13, B1h1, B1l1);

    const bf16x8* Ap = (const bf16x8*)Asm;

    f32x4 acc0[4], acc1[4];
#pragma unroll
    for (int tt = 0; tt < 4; ++tt) {
        // A fragments for this tile from LDS (canonical lane*16B pattern)
        const bf16x8 ah0 = Ap[(tt * 2 + 0) * 64 + lane];
        const bf16x8 ah1 = Ap[(tt * 2 + 1) * 64 + lane];
        const bf16x8 al0 = Ap[512 + (tt * 2 + 0) * 64 + lane];
        const bf16x8 al1 = Ap[512 + (tt * 2 + 1) * 64 + lane];

        f32x4 a = {0.f, 0.f, 0.f, 0.f};
        f32x4 b = {0.f, 0.f, 0.f, 0.f};
        // two independent 6-deep chains interleave -> hides MFMA latency
        a = __builtin_amdgcn_mfma_f32_16x16x32_bf16(ah0, B0h0, a, 0, 0, 0);
        b = __builtin_amdgcn_mfma_f32_16x16x32_bf16(ah0, B1h0, b, 0, 0, 0);
        a = __builtin_amdgcn_mfma_f32_16x16x32_bf16(ah1, B0h1, a, 0, 0, 0);
        b = __builtin_amdgcn_mfma_f32_16x16x32_bf16(ah1, B1h1, b, 0, 0, 0);
        a = __builtin_amdgcn_mfma_f32_16x16x32_bf16(al0, B0h0, a, 0, 0, 0);
        b = __builtin_amdgcn_mfma_f32_16x16x32_bf16(al0, B1h0, b, 0, 0, 0);
        a = __builtin_amdgcn_mfma_f32_16x16x32_bf16(al1, B0h1, a, 0, 0, 0);
        b = __builtin_amdgcn_mfma_f32_16x16x32_bf16(al1, B1h1, b, 0, 0, 0);
        a = __builtin_amdgcn_mfma_f32_16x16x32_bf16(ah0, B0l0, a, 0, 0, 0);
        b = __builtin_amdgcn_mfma_f32_16x16x32_bf16(ah0, B1l0, b, 0, 0, 0);
        a = __builtin_amdgcn_mfma_f32_16x16x32_bf16(ah1, B0l1, a, 0, 0, 0);
        b = __builtin_amdgcn_mfma_f32_16x16x32_bf16(ah1, B1l1, b, 0, 0, 0);
        acc0[tt] = a;
        acc1[tt] = b;
    }

    epilogue(g0,     acc0, rr, odd, qlo, qhi, invf4, out);
    epilogue(g0 + 1, acc1, rr, odd, qlo, qhi, invf4, out);
}

// ---------------------------------------------------------------------------
extern "C" void kernel_launch(void* const* d_in, const int* in_sizes, int n_in,
                              void* d_out, int out_size, void* d_ws, size_t ws_size,
                              hipStream_t stream)
{
    const float* x           = (const float*)d_in[0];
    const float* thetas      = (const float*)d_in[1];
    const float* r_pairs     = (const float*)d_in[2];
    const float* theta_scale = (const float*)d_in[3];
    // d_in[4] = n_rots_scale (unused by the reference)
    const float* r_matrix    = (const float*)d_in[5];
    const float* inv_freq    = (const float*)d_in[6];
    float* out = (float*)d_out;
    unsigned short* Apack = (unsigned short*)d_ws;   // 8192 ushort = 16 KB

    build_pack_kernel<<<1, 256, 0, stream>>>(thetas, r_pairs, theta_scale,
                                             r_matrix, Apack);
    rope_mfma_kernel<<<NBLK, 256, 0, stream>>>(x, Apack, inv_freq, out);
}